// Round 6
// baseline (586.030 us; speedup 1.0000x reference)
//
#include <hip/hip_runtime.h>
#include <math.h>

// Problem constants
constexpr int Bc   = 8;
constexpr int Sc   = 1024;
constexpr int HIDc = 1024;
constexpr int NHc  = 16;
constexpr int DHc  = 64;
constexpr int Mc   = Bc * Sc;                 // 8192 rows for all GEMMs
constexpr int Kc2  = 1024;                    // K dim for all GEMMs
constexpr float SCALE    = 8.0f;              // ref divides by DH**-0.5 == *sqrt(64)
constexpr float EPS_TERM = 1024.0f * 1e-8f;   // S * ZERO in the renorm denominator

typedef short s16x8 __attribute__((ext_vector_type(8)));   // 8 bf16 (4 VGPRs)
typedef float f32x4 __attribute__((ext_vector_type(4)));

__device__ __forceinline__ ushort f2bf(float f) {          // RNE float->bf16 bits
  unsigned u = __float_as_uint(f);
  u += 0x7FFFu + ((u >> 16) & 1u);
  return (ushort)(u >> 16);
}
__device__ __forceinline__ float bf2f(ushort h) {
  return __uint_as_float(((unsigned)h) << 16);
}
__device__ __forceinline__ unsigned pk2bf(float a, float b) {  // pack 2 bf16
  return (unsigned)f2bf(a) | ((unsigned)f2bf(b) << 16);
}

// async global->LDS, 16B per lane; LDS dest = wave-uniform base + lane*16
__device__ __forceinline__ void gl_lds16(const ushort* g, ushort* l) {
  __builtin_amdgcn_global_load_lds(
      (const __attribute__((address_space(1))) void*)g,
      (__attribute__((address_space(3))) void*)l, 16, 0, 0);
}

// split 8 fp32 -> bf16 hi8 + lo8 (RNE)
__device__ __forceinline__ void split8(const float4 v0, const float4 v1,
                                       s16x8& hi, s16x8& lo) {
  const float f[8] = {v0.x, v0.y, v0.z, v0.w, v1.x, v1.y, v1.z, v1.w};
  ushort h[8], l[8];
#pragma unroll
  for (int i = 0; i < 8; i++) {
    h[i] = f2bf(f[i]);
    l[i] = f2bf(f[i] - bf2f(h[i]));
  }
#pragma unroll
  for (int i = 0; i < 8; i++) { hi[i] = (short)h[i]; lo[i] = (short)l[i]; }
}

// ---------------------------------------------------------------------------
// Weight conversions (one launch): seg 0=Wq(split) 1=Wk(split) 2=Wv 3=Wo
// ---------------------------------------------------------------------------
__global__ __launch_bounds__(256) void cvt_weights(
    const float4* __restrict__ Wq, const float4* __restrict__ Wk,
    const float4* __restrict__ Wv, const float4* __restrict__ Wo,
    ushort4* __restrict__ Wqh, ushort4* __restrict__ Wql,
    ushort4* __restrict__ Wkh, ushort4* __restrict__ Wkl,
    ushort4* __restrict__ Wvh, ushort4* __restrict__ Woh, int n4w)
{
  const int bpseg = n4w / 256;                 // blocks per segment (1024)
  const int seg   = blockIdx.x / bpseg;
  const int li    = (blockIdx.x - seg * bpseg) * 256 + threadIdx.x;
  if (li >= n4w) return;
  if (seg == 0) {
    const float4 v = Wq[li];
    ushort4 h, l;
    h.x = f2bf(v.x); l.x = f2bf(v.x - bf2f(h.x));
    h.y = f2bf(v.y); l.y = f2bf(v.y - bf2f(h.y));
    h.z = f2bf(v.z); l.z = f2bf(v.z - bf2f(h.z));
    h.w = f2bf(v.w); l.w = f2bf(v.w - bf2f(h.w));
    Wqh[li] = h; Wql[li] = l;
  } else if (seg == 1) {
    const float4 v = Wk[li];
    ushort4 h, l;
    h.x = f2bf(v.x); l.x = f2bf(v.x - bf2f(h.x));
    h.y = f2bf(v.y); l.y = f2bf(v.y - bf2f(h.y));
    h.z = f2bf(v.z); l.z = f2bf(v.z - bf2f(h.z));
    h.w = f2bf(v.w); l.w = f2bf(v.w - bf2f(h.w));
    Wkh[li] = h; Wkl[li] = l;
  } else {
    const float4 v = (seg == 2) ? Wv[li] : Wo[li];
    ushort4 h;
    h.x = f2bf(v.x); h.y = f2bf(v.y); h.z = f2bf(v.z); h.w = f2bf(v.w);
    if (seg == 2) Wvh[li] = h; else Woh[li] = h;
  }
}

// ---------------------------------------------------------------------------
// Input split pass: seg 0=Q(split hi/lo) 1=K(split hi/lo) 2=V(hi only).
// ---------------------------------------------------------------------------
__global__ __launch_bounds__(256) void cvt_inputs(
    const float4* __restrict__ Qf, const float4* __restrict__ Kf,
    const float4* __restrict__ Vf,
    s16x8* __restrict__ Qsh, s16x8* __restrict__ Qsl,
    s16x8* __restrict__ Ksh, s16x8* __restrict__ Ksl,
    s16x8* __restrict__ Vsh, int n8)
{
  const int bpseg = n8 / 256;                  // 4096 blocks per segment
  const int seg   = blockIdx.x / bpseg;
  const int li    = (blockIdx.x - seg * bpseg) * 256 + threadIdx.x;
  if (li >= n8) return;
  const float4* src = (seg == 0) ? Qf : (seg == 1) ? Kf : Vf;
  const float4 v0 = src[2 * li];
  const float4 v1 = src[2 * li + 1];
  if (seg < 2) {
    s16x8 hi, lo;
    split8(v0, v1, hi, lo);
    if (seg == 0) { Qsh[li] = hi; Qsl[li] = lo; }
    else          { Ksh[li] = hi; Ksl[li] = lo; }
  } else {
    const float f[8] = {v0.x, v0.y, v0.z, v0.w, v1.x, v1.y, v1.z, v1.w};
    s16x8 hi;
#pragma unroll
    for (int i = 0; i < 8; i++) hi[i] = (short)f2bf(f[i]);
    Vsh[li] = hi;
  }
}

// ---------------------------------------------------------------------------
// Fused QKV projection GEMM — ROUND-3 EXACT (known-good 228 us).
// 128x128 tile, 4 waves 2x2 of 64x64, BK=32, 2-phase dbuf, XCD swizzle.
// Structure pinned at ~225 us across r2/r3/r5 knob sweeps (1-phase/2-phase/
// occupancy): the 2-phase structural ceiling (m233). Next step would be the
// 8-phase counted-vmcnt template — needs a 4-stream LDS redesign, parked.
// ---------------------------------------------------------------------------
__global__ __launch_bounds__(256, 2) void qkv_gemm(
    const ushort* __restrict__ Qsh, const ushort* __restrict__ Qsl,
    const ushort* __restrict__ Ksh, const ushort* __restrict__ Ksl,
    const ushort* __restrict__ Vsh,
    const ushort* __restrict__ Wqh, const ushort* __restrict__ Wql,
    const ushort* __restrict__ Wkh, const ushort* __restrict__ Wkl,
    const ushort* __restrict__ Wvh,
    const float* __restrict__ bq, const float* __restrict__ bk,
    const float* __restrict__ bv,
    ushort* __restrict__ qhi, ushort* __restrict__ qlo,
    ushort* __restrict__ khi, ushort* __restrict__ klo,
    ushort* __restrict__ vt)
{
  __shared__ ushort AhL[2][4096];
  __shared__ ushort BhL[2][4096];
  __shared__ ushort AlL[2][4096];
  __shared__ ushort BlL[2][4096];

  const int bid = blockIdx.x;                  // 0..1535
  const int wid = (bid & 7) * 192 + (bid >> 3);
  const int z   = wid >> 9;                    // 0..2
  const int rem = wid & 511;
  const int m0  = (rem >> 3) * 128;
  const int n0  = (rem & 7) * 128;

  const bool split = (z < 2);
  const ushort* Ah = (z == 0) ? Qsh : (z == 1) ? Ksh : Vsh;
  const ushort* Al = (z == 0) ? Qsl : Ksl;     // unused when z==2
  const ushort* Bh = (z == 0) ? Wqh : (z == 1) ? Wkh : Wvh;
  const ushort* Bl = (z == 0) ? Wql : Wkl;     // unused when z==2
  const float* bias = (z == 0) ? bq : (z == 1) ? bk : bv;

  const int t    = threadIdx.x;
  const int w    = t >> 6;
  const int ln   = t & 63;
  const int col  = ln & 15;
  const int quad = ln >> 4;
  const int wm   = w >> 1, wn = w & 1;

  f32x4 acc[4][4] = {};

  const int sA = w * 128;  // this wave's 128-chunk staging range

  auto STAGE = [&](int buf, int k0) {
#pragma unroll
    for (int j = 0; j < 2; j++) {
      const int s = sA + j * 64 + ln;
      const int r = s & 127, c = s >> 7;
      const int ldst = (sA + j * 64) * 8;      // wave-uniform LDS base
      const size_t goA = (size_t)(m0 + r) * Kc2 + k0 + c * 8;
      const size_t goB = (size_t)(n0 + r) * Kc2 + k0 + c * 8;
      gl_lds16(Ah + goA, &AhL[buf][ldst]);
      gl_lds16(Bh + goB, &BhL[buf][ldst]);
      if (split) {
        gl_lds16(Al + goA, &AlL[buf][ldst]);
        gl_lds16(Bl + goB, &BlL[buf][ldst]);
      }
    }
  };

  auto COMPUTE = [&](int buf) {
    s16x8 a_h[4], b_h[4], a_l[4], b_l[4];
#pragma unroll
    for (int i = 0; i < 4; i++) {
      const int ai = (quad * 128 + wm * 64 + i * 16 + col) * 8;
      const int bi = (quad * 128 + wn * 64 + i * 16 + col) * 8;
      a_h[i] = *(const s16x8*)&AhL[buf][ai];
      b_h[i] = *(const s16x8*)&BhL[buf][bi];
      if (split) {
        a_l[i] = *(const s16x8*)&AlL[buf][ai];
        b_l[i] = *(const s16x8*)&BlL[buf][bi];
      }
    }
#pragma unroll
    for (int i = 0; i < 4; i++)
#pragma unroll
      for (int jj = 0; jj < 4; jj++) {
        acc[i][jj] = __builtin_amdgcn_mfma_f32_16x16x32_bf16(a_h[i], b_h[jj], acc[i][jj], 0, 0, 0);
        if (split) {
          acc[i][jj] = __builtin_amdgcn_mfma_f32_16x16x32_bf16(a_h[i], b_l[jj], acc[i][jj], 0, 0, 0);
          acc[i][jj] = __builtin_amdgcn_mfma_f32_16x16x32_bf16(a_l[i], b_h[jj], acc[i][jj], 0, 0, 0);
        }
      }
  };

  // 2-phase pipeline: 32 K-tiles, one barrier per tile.
  STAGE(0, 0);
  __syncthreads();                 // drains vmcnt(0): tile 0 landed
  int cur = 0;
  for (int kt = 0; kt < 31; ++kt) {
    STAGE(cur ^ 1, (kt + 1) * 32); // next tile in flight during MFMAs
    COMPUTE(cur);
    __syncthreads();               // drain after compute: overlap captured
    cur ^= 1;
  }
  COMPUTE(cur);

  // epilogue: C/D frag mapping col=lane&15, row=quad*4+reg
  const int mb = m0 + wm * 64;
  const int nb = n0 + wn * 64;
  ushort* Ch = (z == 0) ? qhi : khi;
  ushort* Cl = (z == 0) ? qlo : klo;
#pragma unroll
  for (int i = 0; i < 4; i++)
#pragma unroll
    for (int jj = 0; jj < 4; jj++) {
      const int n  = nb + jj * 16 + col;
      const float bvv = bias[n];
#pragma unroll
      for (int r = 0; r < 4; r++) {
        const int m   = mb + i * 16 + quad * 4 + r;
        const float v = acc[i][jj][r] + bvv;
        const int b_ = m >> 10, s = m & (Sc - 1);
        const int h_ = n >> 6,  d = n & (DHc - 1);
        if (split) {
          const size_t off = (((size_t)b_ * NHc + h_) * Sc + s) * DHc + d;
          const ushort hb = f2bf(v);
          Ch[off] = hb;
          Cl[off] = f2bf(v - bf2f(hb));
        } else {  // transposed V
          const size_t off = (((size_t)b_ * NHc + h_) * DHc + d) * Sc + s;
          vt[off] = f2bf(v);
        }
      }
    }
}

// ---------------------------------------------------------------------------
// Output GEMM: out[m][n] = sum_k ctx[m][k]*Wo[n][k] + bo[n], ctx bf16, out fp32
// 2-phase dbuf pipeline + XCD swizzle. 32 KB LDS. (unchanged)
// ---------------------------------------------------------------------------
__global__ __launch_bounds__(256, 3) void o_gemm(
    const ushort* __restrict__ Ag, const ushort* __restrict__ Bg,
    const float* __restrict__ bias, float* __restrict__ C)
{
  __shared__ ushort AhL[2][4096];
  __shared__ ushort BhL[2][4096];

  const int bid = blockIdx.x;                  // 0..511
  const int wid = (bid & 7) * 64 + (bid >> 3);
  const int m0  = (wid >> 3) * 128;
  const int n0  = (wid & 7) * 128;

  const int t    = threadIdx.x;
  const int w    = t >> 6;
  const int ln   = t & 63;
  const int col  = ln & 15;
  const int quad = ln >> 4;
  const int wm   = w >> 1, wn = w & 1;

  f32x4 acc[4][4] = {};
  const int sA = w * 128;

  auto STAGE = [&](int buf, int k0) {
#pragma unroll
    for (int j = 0; j < 2; j++) {
      const int s = sA + j * 64 + ln;
      const int r = s & 127, c = s >> 7;
      const int ldst = (sA + j * 64) * 8;
      gl_lds16(Ag + (size_t)(m0 + r) * Kc2 + k0 + c * 8, &AhL[buf][ldst]);
      gl_lds16(Bg + (size_t)(n0 + r) * Kc2 + k0 + c * 8, &BhL[buf][ldst]);
    }
  };

  auto COMPUTE = [&](int buf) {
    s16x8 a_h[4], b_h[4];
#pragma unroll
    for (int i = 0; i < 4; i++) {
      a_h[i] = *(const s16x8*)&AhL[buf][(quad * 128 + wm * 64 + i * 16 + col) * 8];
      b_h[i] = *(const s16x8*)&BhL[buf][(quad * 128 + wn * 64 + i * 16 + col) * 8];
    }
#pragma unroll
    for (int i = 0; i < 4; i++)
#pragma unroll
      for (int jj = 0; jj < 4; jj++)
        acc[i][jj] = __builtin_amdgcn_mfma_f32_16x16x32_bf16(a_h[i], b_h[jj], acc[i][jj], 0, 0, 0);
  };

  STAGE(0, 0);
  __syncthreads();
  int cur = 0;
  for (int kt = 0; kt < 31; ++kt) {
    STAGE(cur ^ 1, (kt + 1) * 32);
    COMPUTE(cur);
    __syncthreads();
    cur ^= 1;
  }
  COMPUTE(cur);

  const int mb = m0 + wm * 64;
  const int nb = n0 + wn * 64;
#pragma unroll
  for (int i = 0; i < 4; i++)
#pragma unroll
    for (int jj = 0; jj < 4; jj++) {
      const int n  = nb + jj * 16 + col;
      const float bvv = bias[n];
#pragma unroll
      for (int r = 0; r < 4; r++) {
        const int m = mb + i * 16 + quad * 4 + r;
        C[(size_t)m * HIDc + n] = acc[i][jj][r] + bvv;
      }
    }
}

// ---------------------------------------------------------------------------
// MFMA flash attention — QBLK=128 (8 waves x 512 threads).
// Staging per block (K/V tile, 24 KB) is UNCHANGED while per-block MFMA work
// doubles: the per-tile barrier+vmcnt-drain cost is amortized over 2x compute
// (the 64->128 tile lever from the GEMM ladder). Block count 2048 -> 1024;
// total attn staging traffic halves. LDS ~43 KB -> 3 blocks/CU = 6 waves/SIMD.
// Per-wave compute identical to the QBLK=64 version (wave-independent
// addressing: quad/col only); staging chunk c = w (8 waves cover 8 chunks).
// ---------------------------------------------------------------------------
constexpr int LDP = 72;   // P LDS row stride (ushorts)

__global__ __launch_bounds__(512, 6) void attn_mfma(
    const ushort* __restrict__ qhi, const ushort* __restrict__ qlo,
    const ushort* __restrict__ khi, const ushort* __restrict__ klo,
    const ushort* __restrict__ vt,  const float* __restrict__ Qm,
    const float* __restrict__ Km,   ushort* __restrict__ ctx)
{
  __shared__ ushort KhiL[4096];     // chunk c*64+r = Khi[r][c*8..+8]
  __shared__ ushort KloL[4096];
  __shared__ ushort VtL [4096];     // chunk c*64+d = V^T[d][c*8..+8]
  __shared__ ushort PmL [128 * LDP];
  __shared__ float  kmL[64];

  const int t    = threadIdx.x;     // 0..511
  const int w    = t >> 6;          // 0..7
  const int ln   = t & 63;
  const int col  = ln & 15;
  const int quad = ln >> 4;

  // XCD-aware remap: 16 whole heads per XCD, q-tiles of a head on one XCD.
  const int id  = blockIdx.x;          // 0..1023
  const int xcd = id & 7;
  const int j   = id >> 3;             // 0..127
  const int bh  = xcd * 16 + (j >> 3);
  const int qt  = j & 7;               // 8 q-tiles of 128 rows
  const int b   = bh >> 4;
  const int h   = bh & 15;

  const int qbase = qt * 128 + w * 16;
  const size_t headoff = (size_t)bh * Sc * DHc;

  s16x8 qh0, qh1, ql0, ql1;
  {
    const size_t ro = headoff + (size_t)(qbase + col) * DHc + quad * 8;
    qh0 = *(const s16x8*)(qhi + ro);
    qh1 = *(const s16x8*)(qhi + ro + 32);
    ql0 = *(const s16x8*)(qlo + ro);
    ql1 = *(const s16x8*)(qlo + ro + 32);
  }

  f32x4 OT[4] = {{0,0,0,0},{0,0,0,0},{0,0,0,0},{0,0,0,0}};
  float mrow = -INFINITY;
  float Zp = 0.0f, Zmp = 0.0f;

  for (int k0 = 0; k0 < Sc; k0 += 64) {
    __syncthreads();
    {
      const int c = w;                 // 8 waves cover the 8 chunks
      const size_t gk = headoff + (size_t)(k0 + ln) * DHc + c * 8;
      const size_t gv = headoff + (size_t)ln * Sc + k0 + c * 8;
      gl_lds16(khi + gk, &KhiL[c * 512]);
      gl_lds16(klo + gk, &KloL[c * 512]);
      gl_lds16(vt  + gv, &VtL [c * 512]);
    }
    if (t < 64) kmL[t] = Km[b * Sc + k0 + t];
    __syncthreads();

    float s[4][4];
#pragma unroll
    for (int ks = 0; ks < 4; ks++) {
      const int base0 = (quad * 64 + ks * 16 + col) * 8;
      const int base1 = ((quad + 4) * 64 + ks * 16 + col) * 8;
      const s16x8 kh0 = *(const s16x8*)&KhiL[base0];
      const s16x8 kh1 = *(const s16x8*)&KhiL[base1];
      const s16x8 kl0 = *(const s16x8*)&KloL[base0];
      const s16x8 kl1 = *(const s16x8*)&KloL[base1];
      f32x4 a = {0,0,0,0};
      a = __builtin_amdgcn_mfma_f32_16x16x32_bf16(kh0, qh0, a, 0, 0, 0);
      a = __builtin_amdgcn_mfma_f32_16x16x32_bf16(kh1, qh1, a, 0, 0, 0);
      a = __builtin_amdgcn_mfma_f32_16x16x32_bf16(kh0, ql0, a, 0, 0, 0);
      a = __builtin_amdgcn_mfma_f32_16x16x32_bf16(kh1, ql1, a, 0, 0, 0);
      a = __builtin_amdgcn_mfma_f32_16x16x32_bf16(kl0, qh0, a, 0, 0, 0);
      a = __builtin_amdgcn_mfma_f32_16x16x32_bf16(kl1, qh1, a, 0, 0, 0);
#pragma unroll
      for (int r = 0; r < 4; r++) s[ks][r] = a[r] * SCALE;
    }

    float tmax = s[0][0];
#pragma unroll
    for (int ks = 0; ks < 4; ks++)
#pragma unroll
      for (int r = 0; r < 4; r++) tmax = fmaxf(tmax, s[ks][r]);
    tmax = fmaxf(tmax, __shfl_xor(tmax, 16, 64));
    tmax = fmaxf(tmax, __shfl_xor(tmax, 32, 64));

    const float mn    = fmaxf(mrow, tmax);
    const float alpha = __expf(mrow - mn);
    mrow = mn;

    float ps = 0.0f, pms = 0.0f;
    const int prow = (w * 16 + col) * LDP;
#pragma unroll
    for (int ks = 0; ks < 4; ks++) {
      const float4 km4 = *(const float4*)&kmL[ks * 16 + quad * 4];
      const float p0 = __expf(s[ks][0] - mn), p1 = __expf(s[ks][1] - mn);
      const float p2 = __expf(s[ks][2] - mn), p3 = __expf(s[ks][3] - mn);
      const float q0 = p0 * km4.x, q1 = p1 * km4.y, q2 = p2 * km4.z, q3 = p3 * km4.w;
      ps  += (p0 + p1) + (p2 + p3);
      pms += (q0 + q1) + (q2 + q3);
      uint2 pv;
      pv.x = pk2bf(q0, q1);
      pv.y = pk2bf(q2, q3);
      *(uint2*)&PmL[prow + ks * 16 + quad * 4] = pv;
    }
    Zp  = Zp  * alpha + ps;
    Zmp = Zmp * alpha + pms;
#pragma unroll
    for (int dt = 0; dt < 4; dt++) OT[dt] *= alpha;

    const s16x8 p0 = *(const s16x8*)&PmL[prow + quad * 8];
    const s16x8 p1 = *(const s16x8*)&PmL[prow + 32 + quad * 8];
#pragma unroll
    for (int dt = 0; dt < 4; dt++) {
      const s16x8 a0 = *(const s16x8*)&VtL[(quad * 64 + dt * 16 + col) * 8];
      const s16x8 a1 = *(const s16x8*)&VtL[((quad + 4) * 64 + dt * 16 + col) * 8];
      OT[dt] = __builtin_amdgcn_mfma_f32_16x16x32_bf16(a0, p0, OT[dt], 0, 0, 0);
      OT[dt] = __builtin_amdgcn_mfma_f32_16x16x32_bf16(a1, p1, OT[dt], 0, 0, 0);
    }
  }

  Zp  += __shfl_xor(Zp,  16, 64);  Zp  += __shfl_xor(Zp,  32, 64);
  Zmp += __shfl_xor(Zmp, 16, 64);  Zmp += __shfl_xor(Zmp, 32, 64);

  const int q     = qbase + col;
  const float qmv = Qm[b * Sc + q];
  const float rden = (qmv != 0.0f) ? 1.0f / (Zmp + EPS_TERM * Zp) : 0.0f;

  ushort* crow = ctx + (size_t)(b * Sc + q) * HIDc + h * DHc + quad * 4;
#pragma unroll
  for (int dt = 0; dt < 4; dt++) {
    uint2 ov;
    ov.x = pk2bf(OT[dt][0] * rden, OT[dt][1] * rden);
    ov.y = pk2bf(OT[dt][2] * rden, OT[dt][3] * rden);
    *(uint2*)(crow + dt * 16) = ov;
  }
}

// ---------------------------------------------------------------------------
extern "C" void kernel_launch(void* const* d_in, const int* in_sizes, int n_in,
                              void* d_out, int out_size, void* d_ws, size_t ws_size,
                              hipStream_t stream)
{
  const float* Q  = (const float*)d_in[0];
  const float* K  = (const float*)d_in[1];
  const float* V  = (const float*)d_in[2];
  const float* Qm = (const float*)d_in[3];
  const float* Km = (const float*)d_in[4];
  const float* Wq = (const float*)d_in[5];
  const float* bq = (const float*)d_in[6];
  const float* Wk = (const float*)d_in[7];
  const float* bk = (const float*)d_in[8];
  const float* Wv = (const float*)d_in[9];
  const float* bv = (const float*)d_in[10];
  const float* Wo = (const float*)d_in[11];
  const float* bo = (const float*)d_in[12];
  float* out = (float*)d_out;

  const size_t NEL = (size_t)Mc * HIDc;   // 8.39M
  const size_t WEL = (size_t)HIDc * HIDc; // 1.05M

  // weights (6*WEL)
  ushort* Wqh = (ushort*)d_ws;
  ushort* Wql = Wqh + WEL;
  ushort* Wkh = Wql + WEL;
  ushort* Wkl = Wkh + WEL;
  ushort* Wvh = Wkl + WEL;
  ushort* Woh = Wvh + WEL;
  // pre-split inputs (5*NEL) — dead after qkv_gemm
  ushort* Qsh = Woh + WEL;
  ushort* Qsl = Qsh + NEL;
  ushort* Ksh = Qsl + NEL;
  ushort* Ksl = Ksh + NEL;
  ushort* Vsh = Ksl + NEL;
  // projected tensors (5*NEL)
  ushort* qhi = Vsh + NEL;
  ushort* qlo = qhi + NEL;
  ushort* khi = qlo + NEL;
  ushort* klo = khi + NEL;
  ushort* vt  = klo + NEL;
  // ctx aliases the dead Q-split region (written by attn, after qkv_gemm done)
  ushort* ctx = Qsh;
  // total: 6*WEL + 10*NEL ushorts ~= 180 MB

  const int n4w = (int)(WEL / 4);   // 262144 -> 1024 blocks/segment

  cvt_weights<<<4 * (n4w / 256), 256, 0, stream>>>(
      (const float4*)Wq, (const float4*)Wk, (const float4*)Wv, (const float4*)Wo,
      (ushort4*)Wqh, (ushort4*)Wql, (ushort4*)Wkh, (ushort4*)Wkl,
      (ushort4*)Wvh, (ushort4*)Woh, n4w);

  // pre-split Q/K (hi/lo) and V (hi) to bf16, row-major [M][K]
  const int n8 = (int)(NEL / 8);    // 1048576 -> 4096 blocks/segment
  cvt_inputs<<<3 * (n8 / 256), 256, 0, stream>>>(
      (const float4*)Q, (const float4*)K, (const float4*)V,
      (s16x8*)Qsh, (s16x8*)Qsl, (s16x8*)Ksh, (s16x8*)Ksl, (s16x8*)Vsh, n8);

  // fused QKV projections (round-3 known-good)
  qkv_gemm<<<dim3(3 * (Mc / 128) * (HIDc / 128)), 256, 0, stream>>>(
      Qsh, Qsl, Ksh, Ksl, Vsh,
      Wqh, Wql, Wkh, Wkl, Wvh, bq, bk, bv, qhi, qlo, khi, klo, vt);

  // attention -> bf16 ctx (QBLK=128, 8 waves)
  attn_mfma<<<Bc * NHc * (Sc / 128), 512, 0, stream>>>(qhi, qlo, khi, klo, vt, Qm, Km, ctx);

  // output projection (2-phase dbuf pipeline)
  o_gemm<<<dim3((Mc / 128) * (HIDc / 128)), 256, 0, stream>>>(ctx, Woh, bo, out);
}

// Round 8
// 526.179 us; speedup vs baseline: 1.1137x; 1.1137x over previous
//
#include <hip/hip_runtime.h>
#include <math.h>

// Problem constants
constexpr int Bc   = 8;
constexpr int Sc   = 1024;
constexpr int HIDc = 1024;
constexpr int NHc  = 16;
constexpr int DHc  = 64;
constexpr int Mc   = Bc * Sc;                 // 8192 rows for all GEMMs
constexpr int Kc2  = 1024;                    // K dim for all GEMMs
constexpr float SCALE    = 8.0f;              // ref divides by DH**-0.5 == *sqrt(64)
constexpr float EPS_TERM = 1024.0f * 1e-8f;   // S * ZERO in the renorm denominator

typedef short s16x8 __attribute__((ext_vector_type(8)));   // 8 bf16 (4 VGPRs)
typedef float f32x4 __attribute__((ext_vector_type(4)));

__device__ __forceinline__ ushort f2bf(float f) {          // RNE float->bf16 bits
  unsigned u = __float_as_uint(f);
  u += 0x7FFFu + ((u >> 16) & 1u);
  return (ushort)(u >> 16);
}
__device__ __forceinline__ float bf2f(ushort h) {
  return __uint_as_float(((unsigned)h) << 16);
}
__device__ __forceinline__ unsigned pk2bf(float a, float b) {  // pack 2 bf16
  return (unsigned)f2bf(a) | ((unsigned)f2bf(b) << 16);
}

// async global->LDS, 16B per lane; LDS dest = wave-uniform base + lane*16
__device__ __forceinline__ void gl_lds16(const ushort* g, ushort* l) {
  __builtin_amdgcn_global_load_lds(
      (const __attribute__((address_space(1))) void*)g,
      (__attribute__((address_space(3))) void*)l, 16, 0, 0);
}

// split 8 fp32 -> bf16 hi8 + lo8 (RNE)
__device__ __forceinline__ void split8(const float4 v0, const float4 v1,
                                       s16x8& hi, s16x8& lo) {
  const float f[8] = {v0.x, v0.y, v0.z, v0.w, v1.x, v1.y, v1.z, v1.w};
  ushort h[8], l[8];
#pragma unroll
  for (int i = 0; i < 8; i++) {
    h[i] = f2bf(f[i]);
    l[i] = f2bf(f[i] - bf2f(h[i]));
  }
#pragma unroll
  for (int i = 0; i < 8; i++) { hi[i] = (short)h[i]; lo[i] = (short)l[i]; }
}

// ---------------------------------------------------------------------------
// Fused conversion pass (one launch): blocks 0..4095 convert weights
// (seg 0=Wq split, 1=Wk split, 2=Wv, 3=Wo); blocks 4096..16383 convert
// inputs (seg 0=Q split, 1=K split, 2=V). Both memory-bound; fusing removes
// one launch gap. Branch is block-uniform.
// ---------------------------------------------------------------------------
__global__ __launch_bounds__(256) void cvt_all(
    const float4* __restrict__ Wq, const float4* __restrict__ Wk,
    const float4* __restrict__ Wv, const float4* __restrict__ Wo,
    ushort4* __restrict__ Wqh, ushort4* __restrict__ Wql,
    ushort4* __restrict__ Wkh, ushort4* __restrict__ Wkl,
    ushort4* __restrict__ Wvh, ushort4* __restrict__ Woh,
    const float4* __restrict__ Qf, const float4* __restrict__ Kf,
    const float4* __restrict__ Vf,
    s16x8* __restrict__ Qsh, s16x8* __restrict__ Qsl,
    s16x8* __restrict__ Ksh, s16x8* __restrict__ Ksl,
    s16x8* __restrict__ Vsh)
{
  const int bid = blockIdx.x;
  if (bid < 4096) {
    // weights: n4w = 262144 float4 per matrix, 1024 blocks/segment
    const int seg = bid >> 10;
    const int li  = (bid & 1023) * 256 + threadIdx.x;
    if (seg == 0) {
      const float4 v = Wq[li];
      ushort4 h, l;
      h.x = f2bf(v.x); l.x = f2bf(v.x - bf2f(h.x));
      h.y = f2bf(v.y); l.y = f2bf(v.y - bf2f(h.y));
      h.z = f2bf(v.z); l.z = f2bf(v.z - bf2f(h.z));
      h.w = f2bf(v.w); l.w = f2bf(v.w - bf2f(h.w));
      Wqh[li] = h; Wql[li] = l;
    } else if (seg == 1) {
      const float4 v = Wk[li];
      ushort4 h, l;
      h.x = f2bf(v.x); l.x = f2bf(v.x - bf2f(h.x));
      h.y = f2bf(v.y); l.y = f2bf(v.y - bf2f(h.y));
      h.z = f2bf(v.z); l.z = f2bf(v.z - bf2f(h.z));
      h.w = f2bf(v.w); l.w = f2bf(v.w - bf2f(h.w));
      Wkh[li] = h; Wkl[li] = l;
    } else {
      const float4 v = (seg == 2) ? Wv[li] : Wo[li];
      ushort4 h;
      h.x = f2bf(v.x); h.y = f2bf(v.y); h.z = f2bf(v.z); h.w = f2bf(v.w);
      if (seg == 2) Wvh[li] = h; else Woh[li] = h;
    }
  } else {
    // inputs: n8 = 1048576 s16x8 per tensor, 4096 blocks/segment
    const int r   = bid - 4096;
    const int seg = r >> 12;
    const int li  = (r & 4095) * 256 + threadIdx.x;
    const float4* src = (seg == 0) ? Qf : (seg == 1) ? Kf : Vf;
    const float4 v0 = src[2 * li];
    const float4 v1 = src[2 * li + 1];
    if (seg < 2) {
      s16x8 hi, lo;
      split8(v0, v1, hi, lo);
      if (seg == 0) { Qsh[li] = hi; Qsl[li] = lo; }
      else          { Ksh[li] = hi; Ksl[li] = lo; }
    } else {
      const float f[8] = {v0.x, v0.y, v0.z, v0.w, v1.x, v1.y, v1.z, v1.w};
      s16x8 hi;
#pragma unroll
      for (int i = 0; i < 8; i++) hi[i] = (short)f2bf(f[i]);
      Vsh[li] = hi;
    }
  }
}

// ---------------------------------------------------------------------------
// Fused QKV projection GEMM — ROUND-3 EXACT (known-good 228 us).
// 128x128 tile, 4 waves 2x2 of 64x64, BK=32, 2-phase dbuf, XCD swizzle.
// Structure pinned at ~225 us across r2/r3/r5/r6 knob sweeps: the 2-phase
// structural ceiling (m233). Next step: 256^2 8-phase template (parked).
// ---------------------------------------------------------------------------
__global__ __launch_bounds__(256, 2) void qkv_gemm(
    const ushort* __restrict__ Qsh, const ushort* __restrict__ Qsl,
    const ushort* __restrict__ Ksh, const ushort* __restrict__ Ksl,
    const ushort* __restrict__ Vsh,
    const ushort* __restrict__ Wqh, const ushort* __restrict__ Wql,
    const ushort* __restrict__ Wkh, const ushort* __restrict__ Wkl,
    const ushort* __restrict__ Wvh,
    const float* __restrict__ bq, const float* __restrict__ bk,
    const float* __restrict__ bv,
    ushort* __restrict__ qhi, ushort* __restrict__ qlo,
    ushort* __restrict__ khi, ushort* __restrict__ klo,
    ushort* __restrict__ vt)
{
  __shared__ ushort AhL[2][4096];
  __shared__ ushort BhL[2][4096];
  __shared__ ushort AlL[2][4096];
  __shared__ ushort BlL[2][4096];

  const int bid = blockIdx.x;                  // 0..1535
  const int wid = (bid & 7) * 192 + (bid >> 3);
  const int z   = wid >> 9;                    // 0..2
  const int rem = wid & 511;
  const int m0  = (rem >> 3) * 128;
  const int n0  = (rem & 7) * 128;

  const bool split = (z < 2);
  const ushort* Ah = (z == 0) ? Qsh : (z == 1) ? Ksh : Vsh;
  const ushort* Al = (z == 0) ? Qsl : Ksl;     // unused when z==2
  const ushort* Bh = (z == 0) ? Wqh : (z == 1) ? Wkh : Wvh;
  const ushort* Bl = (z == 0) ? Wql : Wkl;     // unused when z==2
  const float* bias = (z == 0) ? bq : (z == 1) ? bk : bv;

  const int t    = threadIdx.x;
  const int w    = t >> 6;
  const int ln   = t & 63;
  const int col  = ln & 15;
  const int quad = ln >> 4;
  const int wm   = w >> 1, wn = w & 1;

  f32x4 acc[4][4] = {};

  const int sA = w * 128;  // this wave's 128-chunk staging range

  auto STAGE = [&](int buf, int k0) {
#pragma unroll
    for (int j = 0; j < 2; j++) {
      const int s = sA + j * 64 + ln;
      const int r = s & 127, c = s >> 7;
      const int ldst = (sA + j * 64) * 8;      // wave-uniform LDS base
      const size_t goA = (size_t)(m0 + r) * Kc2 + k0 + c * 8;
      const size_t goB = (size_t)(n0 + r) * Kc2 + k0 + c * 8;
      gl_lds16(Ah + goA, &AhL[buf][ldst]);
      gl_lds16(Bh + goB, &BhL[buf][ldst]);
      if (split) {
        gl_lds16(Al + goA, &AlL[buf][ldst]);
        gl_lds16(Bl + goB, &BlL[buf][ldst]);
      }
    }
  };

  auto COMPUTE = [&](int buf) {
    s16x8 a_h[4], b_h[4], a_l[4], b_l[4];
#pragma unroll
    for (int i = 0; i < 4; i++) {
      const int ai = (quad * 128 + wm * 64 + i * 16 + col) * 8;
      const int bi = (quad * 128 + wn * 64 + i * 16 + col) * 8;
      a_h[i] = *(const s16x8*)&AhL[buf][ai];
      b_h[i] = *(const s16x8*)&BhL[buf][bi];
      if (split) {
        a_l[i] = *(const s16x8*)&AlL[buf][ai];
        b_l[i] = *(const s16x8*)&BlL[buf][bi];
      }
    }
#pragma unroll
    for (int i = 0; i < 4; i++)
#pragma unroll
      for (int jj = 0; jj < 4; jj++) {
        acc[i][jj] = __builtin_amdgcn_mfma_f32_16x16x32_bf16(a_h[i], b_h[jj], acc[i][jj], 0, 0, 0);
        if (split) {
          acc[i][jj] = __builtin_amdgcn_mfma_f32_16x16x32_bf16(a_h[i], b_l[jj], acc[i][jj], 0, 0, 0);
          acc[i][jj] = __builtin_amdgcn_mfma_f32_16x16x32_bf16(a_l[i], b_h[jj], acc[i][jj], 0, 0, 0);
        }
      }
  };

  // 2-phase pipeline: 32 K-tiles, one barrier per tile.
  STAGE(0, 0);
  __syncthreads();                 // drains vmcnt(0): tile 0 landed
  int cur = 0;
  for (int kt = 0; kt < 31; ++kt) {
    STAGE(cur ^ 1, (kt + 1) * 32); // next tile in flight during MFMAs
    COMPUTE(cur);
    __syncthreads();               // drain after compute: overlap captured
    cur ^= 1;
  }
  COMPUTE(cur);

  // epilogue: C/D frag mapping col=lane&15, row=quad*4+reg
  const int mb = m0 + wm * 64;
  const int nb = n0 + wn * 64;
  ushort* Ch = (z == 0) ? qhi : khi;
  ushort* Cl = (z == 0) ? qlo : klo;
#pragma unroll
  for (int i = 0; i < 4; i++)
#pragma unroll
    for (int jj = 0; jj < 4; jj++) {
      const int n  = nb + jj * 16 + col;
      const float bvv = bias[n];
#pragma unroll
      for (int r = 0; r < 4; r++) {
        const int m   = mb + i * 16 + quad * 4 + r;
        const float v = acc[i][jj][r] + bvv;
        const int b_ = m >> 10, s = m & (Sc - 1);
        const int h_ = n >> 6,  d = n & (DHc - 1);
        if (split) {
          const size_t off = (((size_t)b_ * NHc + h_) * Sc + s) * DHc + d;
          const ushort hb = f2bf(v);
          Ch[off] = hb;
          Cl[off] = f2bf(v - bf2f(hb));
        } else {  // transposed V
          const size_t off = (((size_t)b_ * NHc + h_) * DHc + d) * Sc + s;
          vt[off] = f2bf(v);
        }
      }
    }
}

// ---------------------------------------------------------------------------
// Output GEMM: out[m][n] = sum_k ctx[m][k]*Wo[n][k] + bo[n], ctx bf16, out fp32
// 2-phase dbuf pipeline + XCD swizzle. 32 KB LDS. (unchanged)
// ---------------------------------------------------------------------------
__global__ __launch_bounds__(256, 3) void o_gemm(
    const ushort* __restrict__ Ag, const ushort* __restrict__ Bg,
    const float* __restrict__ bias, float* __restrict__ C)
{
  __shared__ ushort AhL[2][4096];
  __shared__ ushort BhL[2][4096];

  const int bid = blockIdx.x;                  // 0..511
  const int wid = (bid & 7) * 64 + (bid >> 3);
  const int m0  = (wid >> 3) * 128;
  const int n0  = (wid & 7) * 128;

  const int t    = threadIdx.x;
  const int w    = t >> 6;
  const int ln   = t & 63;
  const int col  = ln & 15;
  const int quad = ln >> 4;
  const int wm   = w >> 1, wn = w & 1;

  f32x4 acc[4][4] = {};
  const int sA = w * 128;

  auto STAGE = [&](int buf, int k0) {
#pragma unroll
    for (int j = 0; j < 2; j++) {
      const int s = sA + j * 64 + ln;
      const int r = s & 127, c = s >> 7;
      const int ldst = (sA + j * 64) * 8;
      gl_lds16(Ag + (size_t)(m0 + r) * Kc2 + k0 + c * 8, &AhL[buf][ldst]);
      gl_lds16(Bg + (size_t)(n0 + r) * Kc2 + k0 + c * 8, &BhL[buf][ldst]);
    }
  };

  auto COMPUTE = [&](int buf) {
    s16x8 a_h[4], b_h[4];
#pragma unroll
    for (int i = 0; i < 4; i++) {
      a_h[i] = *(const s16x8*)&AhL[buf][(quad * 128 + wm * 64 + i * 16 + col) * 8];
      b_h[i] = *(const s16x8*)&BhL[buf][(quad * 128 + wn * 64 + i * 16 + col) * 8];
    }
#pragma unroll
    for (int i = 0; i < 4; i++)
#pragma unroll
      for (int jj = 0; jj < 4; jj++)
        acc[i][jj] = __builtin_amdgcn_mfma_f32_16x16x32_bf16(a_h[i], b_h[jj], acc[i][jj], 0, 0, 0);
  };

  STAGE(0, 0);
  __syncthreads();
  int cur = 0;
  for (int kt = 0; kt < 31; ++kt) {
    STAGE(cur ^ 1, (kt + 1) * 32);
    COMPUTE(cur);
    __syncthreads();
    cur ^= 1;
  }
  COMPUTE(cur);

  const int mb = m0 + wm * 64;
  const int nb = n0 + wn * 64;
#pragma unroll
  for (int i = 0; i < 4; i++)
#pragma unroll
    for (int jj = 0; jj < 4; jj++) {
      const int n  = nb + jj * 16 + col;
      const float bvv = bias[n];
#pragma unroll
      for (int r = 0; r < 4; r++) {
        const int m = mb + i * 16 + quad * 4 + r;
        C[(size_t)m * HIDc + n] = acc[i][jj][r] + bvv;
      }
    }
}

// ---------------------------------------------------------------------------
// MFMA flash attention, S^T orientation — r3 staged structure (QBLK=64,
// 4 waves, 4 blocks/CU) + two additions:
//  * T13 defer-max (THR=8): skip the rescale pass when the running max grew
//    by <= 8. Numerically exact up to bf16 rounding (p/Z invariant to max
//    shift; bf16 relative precision is scale-free). Wave-uniform via __all.
//  * T5 setprio(1) around the two MFMA clusters (m191: helps attn with
//    multiple desynced blocks per CU).
// ---------------------------------------------------------------------------
constexpr int LDP = 72;   // P LDS row stride (ushorts)

__global__ __launch_bounds__(256, 4) void attn_mfma(
    const ushort* __restrict__ qhi, const ushort* __restrict__ qlo,
    const ushort* __restrict__ khi, const ushort* __restrict__ klo,
    const ushort* __restrict__ vt,  const float* __restrict__ Qm,
    const float* __restrict__ Km,   ushort* __restrict__ ctx)
{
  __shared__ ushort KhiL[4096];     // chunk c*64+r = Khi[r][c*8..+8]
  __shared__ ushort KloL[4096];
  __shared__ ushort VtL [4096];     // chunk c*64+d = V^T[d][c*8..+8]
  __shared__ ushort PmL [64 * LDP];
  __shared__ float  kmL[64];

  const int t    = threadIdx.x;
  const int w    = t >> 6;
  const int ln   = t & 63;
  const int col  = ln & 15;
  const int quad = ln >> 4;

  // XCD-aware remap: 16 whole heads per XCD, q-tiles of a head on one XCD.
  const int id  = blockIdx.x;          // 0..2047
  const int xcd = id & 7;
  const int j   = id >> 3;             // 0..255
  const int bh  = xcd * 16 + (j >> 4);
  const int qt  = j & 15;
  const int b   = bh >> 4;
  const int h   = bh & 15;

  const int qbase = qt * 64 + w * 16;
  const size_t headoff = (size_t)bh * Sc * DHc;

  s16x8 qh0, qh1, ql0, ql1;
  {
    const size_t ro = headoff + (size_t)(qbase + col) * DHc + quad * 8;
    qh0 = *(const s16x8*)(qhi + ro);
    qh1 = *(const s16x8*)(qhi + ro + 32);
    ql0 = *(const s16x8*)(qlo + ro);
    ql1 = *(const s16x8*)(qlo + ro + 32);
  }

  f32x4 OT[4] = {{0,0,0,0},{0,0,0,0},{0,0,0,0},{0,0,0,0}};
  float mrow = -INFINITY;
  float Zp = 0.0f, Zmp = 0.0f;

  for (int k0 = 0; k0 < Sc; k0 += 64) {
    __syncthreads();
#pragma unroll
    for (int jj = 0; jj < 2; jj++) {
      const int c = jj * 4 + w;
      const size_t gk = headoff + (size_t)(k0 + ln) * DHc + c * 8;
      const size_t gv = headoff + (size_t)ln * Sc + k0 + c * 8;
      gl_lds16(khi + gk, &KhiL[c * 512]);
      gl_lds16(klo + gk, &KloL[c * 512]);
      gl_lds16(vt  + gv, &VtL [c * 512]);
    }
    if (t < 64) kmL[t] = Km[b * Sc + k0 + t];
    __syncthreads();

    float s[4][4];
    __builtin_amdgcn_s_setprio(1);
#pragma unroll
    for (int ks = 0; ks < 4; ks++) {
      const int base0 = (quad * 64 + ks * 16 + col) * 8;
      const int base1 = ((quad + 4) * 64 + ks * 16 + col) * 8;
      const s16x8 kh0 = *(const s16x8*)&KhiL[base0];
      const s16x8 kh1 = *(const s16x8*)&KhiL[base1];
      const s16x8 kl0 = *(const s16x8*)&KloL[base0];
      const s16x8 kl1 = *(const s16x8*)&KloL[base1];
      f32x4 a = {0,0,0,0};
      a = __builtin_amdgcn_mfma_f32_16x16x32_bf16(kh0, qh0, a, 0, 0, 0);
      a = __builtin_amdgcn_mfma_f32_16x16x32_bf16(kh1, qh1, a, 0, 0, 0);
      a = __builtin_amdgcn_mfma_f32_16x16x32_bf16(kh0, ql0, a, 0, 0, 0);
      a = __builtin_amdgcn_mfma_f32_16x16x32_bf16(kh1, ql1, a, 0, 0, 0);
      a = __builtin_amdgcn_mfma_f32_16x16x32_bf16(kl0, qh0, a, 0, 0, 0);
      a = __builtin_amdgcn_mfma_f32_16x16x32_bf16(kl1, qh1, a, 0, 0, 0);
#pragma unroll
      for (int r = 0; r < 4; r++) s[ks][r] = a[r] * SCALE;
    }
    __builtin_amdgcn_s_setprio(0);

    float tmax = s[0][0];
#pragma unroll
    for (int ks = 0; ks < 4; ks++)
#pragma unroll
      for (int r = 0; r < 4; r++) tmax = fmaxf(tmax, s[ks][r]);
    tmax = fmaxf(tmax, __shfl_xor(tmax, 16, 64));
    tmax = fmaxf(tmax, __shfl_xor(tmax, 32, 64));

    // T13 defer-max: keep old max (exact math, p bounded by e^8) when growth
    // is small; rescale only on real growth. First iter: mrow=-INF -> rescale.
    float mn;
    const bool defer = __all(tmax - mrow <= 8.0f);
    if (defer) {
      mn = mrow;
    } else {
      mn = fmaxf(mrow, tmax);
      const float alpha = __expf(mrow - mn);
      mrow = mn;
      Zp  *= alpha;
      Zmp *= alpha;
#pragma unroll
      for (int dt = 0; dt < 4; dt++) OT[dt] *= alpha;
    }

    float ps = 0.0f, pms = 0.0f;
    const int prow = (w * 16 + col) * LDP;
#pragma unroll
    for (int ks = 0; ks < 4; ks++) {
      const float4 km4 = *(const float4*)&kmL[ks * 16 + quad * 4];
      const float p0 = __expf(s[ks][0] - mn), p1 = __expf(s[ks][1] - mn);
      const float p2 = __expf(s[ks][2] - mn), p3 = __expf(s[ks][3] - mn);
      const float q0 = p0 * km4.x, q1 = p1 * km4.y, q2 = p2 * km4.z, q3 = p3 * km4.w;
      ps  += (p0 + p1) + (p2 + p3);
      pms += (q0 + q1) + (q2 + q3);
      uint2 pv;
      pv.x = pk2bf(q0, q1);
      pv.y = pk2bf(q2, q3);
      *(uint2*)&PmL[prow + ks * 16 + quad * 4] = pv;
    }
    Zp  += ps;
    Zmp += pms;

    const s16x8 p0 = *(const s16x8*)&PmL[prow + quad * 8];
    const s16x8 p1 = *(const s16x8*)&PmL[prow + 32 + quad * 8];
    __builtin_amdgcn_s_setprio(1);
#pragma unroll
    for (int dt = 0; dt < 4; dt++) {
      const s16x8 a0 = *(const s16x8*)&VtL[(quad * 64 + dt * 16 + col) * 8];
      const s16x8 a1 = *(const s16x8*)&VtL[((quad + 4) * 64 + dt * 16 + col) * 8];
      OT[dt] = __builtin_amdgcn_mfma_f32_16x16x32_bf16(a0, p0, OT[dt], 0, 0, 0);
      OT[dt] = __builtin_amdgcn_mfma_f32_16x16x32_bf16(a1, p1, OT[dt], 0, 0, 0);
    }
    __builtin_amdgcn_s_setprio(0);
  }

  Zp  += __shfl_xor(Zp,  16, 64);  Zp  += __shfl_xor(Zp,  32, 64);
  Zmp += __shfl_xor(Zmp, 16, 64);  Zmp += __shfl_xor(Zmp, 32, 64);

  const int q     = qbase + col;
  const float qmv = Qm[b * Sc + q];
  const float rden = (qmv != 0.0f) ? 1.0f / (Zmp + EPS_TERM * Zp) : 0.0f;

  ushort* crow = ctx + (size_t)(b * Sc + q) * HIDc + h * DHc + quad * 4;
#pragma unroll
  for (int dt = 0; dt < 4; dt++) {
    uint2 ov;
    ov.x = pk2bf(OT[dt][0] * rden, OT[dt][1] * rden);
    ov.y = pk2bf(OT[dt][2] * rden, OT[dt][3] * rden);
    *(uint2*)(crow + dt * 16) = ov;
  }
}

// ---------------------------------------------------------------------------
extern "C" void kernel_launch(void* const* d_in, const int* in_sizes, int n_in,
                              void* d_out, int out_size, void* d_ws, size_t ws_size,
                              hipStream_t stream)
{
  const float* Q  = (const float*)d_in[0];
  const float* K  = (const float*)d_in[1];
  const float* V  = (const float*)d_in[2];
  const float* Qm = (const float*)d_in[3];
  const float* Km = (const float*)d_in[4];
  const float* Wq = (const float*)d_in[5];
  const float* bq = (const float*)d_in[6];
  const float* Wk = (const float*)d_in[7];
  const float* bk = (const float*)d_in[8];
  const float* Wv = (const float*)d_in[9];
  const float* bv = (const float*)d_in[10];
  const float* Wo = (const float*)d_in[11];
  const float* bo = (const float*)d_in[12];
  float* out = (float*)d_out;

  const size_t NEL = (size_t)Mc * HIDc;   // 8.39M
  const size_t WEL = (size_t)HIDc * HIDc; // 1.05M

  // weights (6*WEL)
  ushort* Wqh = (ushort*)d_ws;
  ushort* Wql = Wqh + WEL;
  ushort* Wkh = Wql + WEL;
  ushort* Wkl = Wkh + WEL;
  ushort* Wvh = Wkl + WEL;
  ushort* Woh = Wvh + WEL;
  // pre-split inputs (5*NEL) — dead after qkv_gemm
  ushort* Qsh = Woh + WEL;
  ushort* Qsl = Qsh + NEL;
  ushort* Ksh = Qsl + NEL;
  ushort* Ksl = Ksh + NEL;
  ushort* Vsh = Ksl + NEL;
  // projected tensors (5*NEL)
  ushort* qhi = Vsh + NEL;
  ushort* qlo = qhi + NEL;
  ushort* khi = qlo + NEL;
  ushort* klo = khi + NEL;
  ushort* vt  = klo + NEL;
  // ctx aliases the dead Q-split region (written by attn, after qkv_gemm done)
  ushort* ctx = Qsh;
  // total: 6*WEL + 10*NEL ushorts ~= 180 MB

  // fused conversions: 4096 weight blocks + 12288 input blocks
  cvt_all<<<16384, 256, 0, stream>>>(
      (const float4*)Wq, (const float4*)Wk, (const float4*)Wv, (const float4*)Wo,
      (ushort4*)Wqh, (ushort4*)Wql, (ushort4*)Wkh, (ushort4*)Wkl,
      (ushort4*)Wvh, (ushort4*)Woh,
      (const float4*)Q, (const float4*)K, (const float4*)V,
      (s16x8*)Qsh, (s16x8*)Qsl, (s16x8*)Ksh, (s16x8*)Ksl, (s16x8*)Vsh);

  // fused QKV projections (round-3 known-good)
  qkv_gemm<<<dim3(3 * (Mc / 128) * (HIDc / 128)), 256, 0, stream>>>(
      Qsh, Qsl, Ksh, Ksl, Vsh,
      Wqh, Wql, Wkh, Wkl, Wvh, bq, bk, bv, qhi, qlo, khi, klo, vt);

  // attention -> bf16 ctx (QBLK=64 staged + defer-max + setprio)
  attn_mfma<<<Bc * NHc * (Sc / 64), 256, 0, stream>>>(qhi, qlo, khi, klo, vt, Qm, Km, ctx);

  // output projection (2-phase dbuf pipeline)
  o_gemm<<<dim3((Mc / 128) * (HIDc / 128)), 256, 0, stream>>>(ctx, Woh, bo, out);
}